// Round 2
// baseline (259.920 us; speedup 1.0000x reference)
//
#include <hip/hip_runtime.h>
#include <cstdint>

typedef unsigned short ushort_t;
typedef __bf16 bf16x8 __attribute__((ext_vector_type(8)));
typedef ushort_t u16x8 __attribute__((ext_vector_type(8)));
typedef float f32x4 __attribute__((ext_vector_type(4)));
typedef uint32_t u32x4 __attribute__((ext_vector_type(4)));

#define RMS_EPS 1.1920928955078125e-07f
// B=8 T=4096 C=256 Wh=1024 E=8 K=2 ; tokens NT=32768, pairs NP=65536

__device__ __forceinline__ ushort_t f2bf(float f) {
  uint32_t u = __builtin_bit_cast(uint32_t, f);
  u += 0x7fffu + ((u >> 16) & 1u);   // RNE
  return (ushort_t)(u >> 16);
}

__device__ __forceinline__ void g2l16(const ushort_t* g, ushort_t* l) {
  __builtin_amdgcn_global_load_lds(
      (const __attribute__((address_space(1))) uint32_t*)g,
      (__attribute__((address_space(3))) uint32_t*)l, 16, 0, 0);
}

__device__ __forceinline__ f32x4 mfma32(bf16x8 a, bf16x8 b, f32x4 c) {
  return __builtin_amdgcn_mfma_f32_16x16x32_bf16(a, b, c, 0, 0, 0);
}

// GELU sigma-form, identical math to the verified baseline kernel
__device__ __forceinline__ float gelu1(float v) {
  float v2 = v * v;
  float u_ = (0.044715f * v2) * v + v;
  float tq = __expf(-1.5957691216057308f * u_);
  return v * __builtin_amdgcn_rcpf(1.0f + tq);
}

// ---- RMSNorm + cast to bf16: one wave per token ----
__global__ void rmsnorm_cast(const float* __restrict__ x, const float* __restrict__ w,
                             ushort_t* __restrict__ xn) {
  int token = blockIdx.x * 4 + (threadIdx.x >> 6);
  int lane = threadIdx.x & 63;
  const float4* row = reinterpret_cast<const float4*>(x + (size_t)token * 256);
  float4 v = row[lane];
  float s = v.x * v.x + v.y * v.y + v.z * v.z + v.w * v.w;
#pragma unroll
  for (int off = 1; off < 64; off <<= 1) s += __shfl_xor(s, off);
  float inv = rsqrtf(s * (1.0f / 256.0f) + RMS_EPS);
  const float4* wr = reinterpret_cast<const float4*>(w);
  float4 wv = wr[lane];
  ushort4 o;
  o.x = f2bf(v.x * inv * wv.x);
  o.y = f2bf(v.y * inv * wv.y);
  o.z = f2bf(v.z * inv * wv.z);
  o.w = f2bf(v.w * inv * wv.w);
  *reinterpret_cast<ushort4*>(xn + (size_t)token * 256 + lane * 4) = o;
}

// ---- pack W1/W2 into MFMA fragment order via LDS tile (coalesced) ----
// W1 (K=32 frags, unchanged): unit = e*32768 + ch*1024 + kk*128 + nt*64 + lane;
//   elem j = W1[e][kk*32+quad*8+j][ch*32+nt*16+l16]
// W2 (half-interleaved per lane; A-operand of concat-K32 GEMM2):
//   unit U = ((e*32+ch)*16+ct)*64 + lane ; 8 ushorts:
//   elem j   = W2[e][ch*32 +  0 + quad*4+j][ct*16+l16]
//   elem 4+j = W2[e][ch*32 + 16 + quad*4+j][ct*16+l16]
// Block: 64(k) x 128(col) tile. Blocks 0..255: W1 (kt 4 x wt 8), 256..511: W2 (kt 16 x wt 2).
__global__ __launch_bounds__(256) void pack_w(const float* __restrict__ W1,
                                              const float* __restrict__ W2,
                                              ushort_t* __restrict__ w1f,
                                              ushort_t* __restrict__ w2f) {
  __shared__ ushort_t tile[64][130];
  int b = blockIdx.x;
  int isW2 = b >= 256;
  const float* src; ushort_t* dst; int e, kt, wt, rs;
  if (!isW2) { e = b >> 5; kt = (b >> 3) & 3; wt = b & 7; src = W1; dst = w1f; rs = 1024; }
  else { b -= 256; e = b >> 5; kt = (b >> 1) & 15; wt = b & 1; src = W2; dst = w2f; rs = 256; }
  int k0 = kt * 64, c0 = wt * 128;
  const float* sb = src + ((size_t)e << 18) + (size_t)k0 * rs + c0;
  int t = threadIdx.x;
#pragma unroll
  for (int i = 0; i < 8; ++i) {
    int f = i * 1024 + t * 4;          // [0,8192)
    int r = f >> 7, c = f & 127;
    float4 v = *reinterpret_cast<const float4*>(sb + (size_t)r * rs + c);
    ushort2 lo, hi;
    lo.x = f2bf(v.x); lo.y = f2bf(v.y); hi.x = f2bf(v.z); hi.y = f2bf(v.w);
    *reinterpret_cast<ushort2*>(&tile[r][c]) = lo;
    *reinterpret_cast<ushort2*>(&tile[r][c + 2]) = hi;
  }
  __syncthreads();
  int lane = t & 63, l16 = lane & 15, quad = lane >> 4;
  int wave = t >> 6;
  if (!isW2) {
#pragma unroll
    for (int p = 0; p < 4; ++p) {
      int u = p * 256 + t;               // [0,1024)
      int kk2 = (u >> 9) & 1;
      int rr = kk2 * 32 + quad * 8;
      int nt = (u >> 6) & 1, chL = (u >> 7) & 3;
      int cc = chL * 32 + nt * 16 + l16;
      u16x8 o;
#pragma unroll
      for (int j = 0; j < 8; ++j) o[j] = tile[rr + j][cc];
      size_t U = ((size_t)e * 32768) + (size_t)(wt * 4 + chL) * 1024 + (kt * 2 + kk2) * 128 + nt * 64 + lane;
      *reinterpret_cast<u16x8*>(dst + U * 8) = o;
    }
  } else {
#pragma unroll
    for (int p = 0; p < 4; ++p) {
      int u = p * 4 + wave;              // [0,16): chL(2) x ctL(8)
      int chL = u >> 3, ctL = u & 7;
      int cc = ctL * 16 + l16;
      u16x8 o;
#pragma unroll
      for (int j = 0; j < 4; ++j) o[j] = tile[chL * 32 + quad * 4 + j][cc];
#pragma unroll
      for (int j = 0; j < 4; ++j) o[4 + j] = tile[chL * 32 + 16 + quad * 4 + j][cc];
      size_t U = (((size_t)(e * 32 + kt * 2 + chL) * 16) + (wt * 8 + ctL)) * 64 + lane;
      *reinterpret_cast<u16x8*>(dst + U * 8) = o;
    }
  }
}

// ---- route (t,k) pairs into per-expert lists ----
__global__ void route_pairs(const int* __restrict__ eids, int* __restrict__ cnt,
                            int* __restrict__ lists) {
  __shared__ int lcnt[8], lbase[8];
  int tid = threadIdx.x;
  if (tid < 8) lcnt[tid] = 0;
  __syncthreads();
  int p = blockIdx.x * 256 + tid;
  int e = eids[p];
  int lpos = atomicAdd(&lcnt[e], 1);
  __syncthreads();
  if (tid < 8) lbase[tid] = atomicAdd(&cnt[tid], lcnt[tid]);
  __syncthreads();
  lists[e * 65536 + lbase[e] + lpos] = p;
}

// ---- fused expert MLP (operand-swapped, all-K32 MFMA, h stays in registers) ----
// 128 pairs/block, 4 waves x 32 rows. Per 32-w chunk:
//   GEMM1: hT = mfma32(W1frag, xnfrag) -> lane holds h[token=l16][w=nt*16+quad*4+r]
//   GELU in-register, pack nt0|nt1 halves into one bf16x8 (elems 0-3 | 4-7)
//   GEMM2: yT += mfma32(W2frag(half-interleaved), hfrag) — identical (lane,elem)->w
//          map on both operands => exact K=32 dot, no cross-lane traffic.
// W1 double-buffered (g2l16 w16), W2 single-buffered under GEMM1+GELU.
// LDS = 48 KB, regs ~240 incl. acc -> 2 waves/SIMD.
__global__ __launch_bounds__(256, 2) void moe_mlp(
    const ushort_t* __restrict__ xn,   // [32768][256] bf16
    const ushort_t* __restrict__ w1f,  // [8][32][8][2][64][8]
    const ushort_t* __restrict__ w2f,  // [8][32][16][64][8]
    const float* __restrict__ b1,      // [8][1024]
    const float* __restrict__ b2,      // [8][256]
    const int* __restrict__ cnt,       // [8]
    const int* __restrict__ lists,     // [8][65536]
    float* __restrict__ out)           // [65536][256]
{
  __shared__ __align__(16) ushort_t w1b[2][8192];   // 2 x 16KB
  __shared__ __align__(16) ushort_t w2b[8192];      // 1 x 16KB

  int flat = blockIdx.x;
  int e = -1, tile = 0, accum = 0, n_e = 0;
#pragma unroll
  for (int i = 0; i < 8; ++i) {
    int c = cnt[i];
    int t = (c + 127) >> 7;
    if (e < 0 && flat < accum + t) { e = i; tile = flat - accum; n_e = c; }
    accum += t;
  }
  if (e < 0) return;
  int start = tile * 128;

  int tid = threadIdx.x;
  int wave = tid >> 6, lane = tid & 63, l16 = lane & 15, quad = lane >> 4;

  const ushort_t* w1e = w1f + ((size_t)e << 18);
  const ushort_t* w2e = w2f + ((size_t)e << 18);
  const int* le = lists + e * 65536;

  // pair indices, register-resident (token rows keyed by l16 for swapped layout)
  int gi0 = start + wave * 32 + l16;        // mt=0
  int gi1 = gi0 + 16;                       // mt=1
  int pr0 = le[(gi0 < n_e) ? gi0 : 0];
  int pr1 = le[(gi1 < n_e) ? gi1 : 0];

  // stage W1(0) into buffer 0
#pragma unroll
  for (int j = 0; j < 4; ++j) {
    int p = j * 4 + wave;
    g2l16(w1e + p * 512 + lane * 8, &w1b[0][p * 512]);
  }

  // A fragments: 2 m-tiles x full K=256, resident (64 VGPR)
  bf16x8 afr[2][8];
  {
    const u32x4* ar0 = reinterpret_cast<const u32x4*>(xn + (size_t)(pr0 >> 1) * 256);
    const u32x4* ar1 = reinterpret_cast<const u32x4*>(xn + (size_t)(pr1 >> 1) * 256);
#pragma unroll
    for (int kk = 0; kk < 8; ++kk) {
      afr[0][kk] = __builtin_bit_cast(bf16x8, ar0[kk * 4 + quad]);
      afr[1][kk] = __builtin_bit_cast(bf16x8, ar1[kk * 4 + quad]);
    }
  }

  f32x4 acc[2][16];
#pragma unroll
  for (int mt = 0; mt < 2; ++mt)
#pragma unroll
    for (int ct = 0; ct < 16; ++ct) acc[mt][ct] = (f32x4){0.f, 0.f, 0.f, 0.f};

  const float* b1e = b1 + e * 1024;

  for (int ch = 0; ch < 32; ++ch) {
    int cur = ch & 1;
    __syncthreads();   // W1(ch) staged+visible; w2b free (GEMM2(ch-1) reads done)

    // stage W2(ch) -> single buffer (completes under GEMM1+GELU)
    {
      const ushort_t* n2 = w2e + ch * 8192;
#pragma unroll
      for (int j = 0; j < 4; ++j) {
        int p = j * 4 + wave;
        g2l16(n2 + p * 512 + lane * 8, &w2b[p * 512]);
      }
    }
    // stage W1(ch+1) -> alternate buffer
    if (ch + 1 < 32) {
      const ushort_t* n1 = w1e + (ch + 1) * 8192;
#pragma unroll
      for (int j = 0; j < 4; ++j) {
        int p = j * 4 + wave;
        g2l16(n1 + p * 512 + lane * 8, &w1b[cur ^ 1][p * 512]);
      }
    }

    int w0 = ch * 32;
    f32x4 bia0 = *reinterpret_cast<const f32x4*>(b1e + w0 + quad * 4);
    f32x4 bia1 = *reinterpret_cast<const f32x4*>(b1e + w0 + 16 + quad * 4);

    // GEMM1 (swapped): hT[mt][nt] ; 4 independent chains x 8 deep
    const ushort_t* l1 = w1b[cur];
    f32x4 ht00 = (f32x4){0.f, 0.f, 0.f, 0.f};
    f32x4 ht01 = (f32x4){0.f, 0.f, 0.f, 0.f};
    f32x4 ht10 = (f32x4){0.f, 0.f, 0.f, 0.f};
    f32x4 ht11 = (f32x4){0.f, 0.f, 0.f, 0.f};
#pragma unroll
    for (int kk = 0; kk < 8; ++kk) {
      bf16x8 wA = *reinterpret_cast<const bf16x8*>(l1 + ((kk * 2 + 0) * 64 + lane) * 8);
      bf16x8 wB = *reinterpret_cast<const bf16x8*>(l1 + ((kk * 2 + 1) * 64 + lane) * 8);
      ht00 = mfma32(wA, afr[0][kk], ht00);
      ht10 = mfma32(wA, afr[1][kk], ht10);
      ht01 = mfma32(wB, afr[0][kk], ht01);
      ht11 = mfma32(wB, afr[1][kk], ht11);
    }

    // GELU + bf16 pack, all in registers. hF elems 0-3 = nt0 half (w=w0+quad*4+r),
    // elems 4-7 = nt1 half (w=w0+16+quad*4+r) — matches W2 frag interleave exactly.
    u16x8 hp0, hp1;
#pragma unroll
    for (int r = 0; r < 4; ++r) {
      hp0[r]     = f2bf(gelu1(ht00[r] + bia0[r]));
      hp0[4 + r] = f2bf(gelu1(ht01[r] + bia1[r]));
      hp1[r]     = f2bf(gelu1(ht10[r] + bia0[r]));
      hp1[4 + r] = f2bf(gelu1(ht11[r] + bia1[r]));
    }
    bf16x8 hF0 = __builtin_bit_cast(bf16x8, hp0);
    bf16x8 hF1 = __builtin_bit_cast(bf16x8, hp1);

    __syncthreads();   // W2(ch) staged+visible (all waves)

    // GEMM2: yT[32 tok x 256] += W2ᵀ·hT via K=32 MFMA, one b128 read per ct
#pragma unroll
    for (int ct = 0; ct < 16; ++ct) {
      bf16x8 wq = *reinterpret_cast<const bf16x8*>(w2b + (ct * 64 + lane) * 8);
      acc[0][ct] = mfma32(wq, hF0, acc[0][ct]);
      acc[1][ct] = mfma32(wq, hF1, acc[1][ct]);
    }
  }

  // epilogue: +b2, masked float4 scatter store (4 consecutive cols per lane)
  const float* b2e = b2 + e * 256;
#pragma unroll
  for (int mt = 0; mt < 2; ++mt) {
    int gi = mt ? gi1 : gi0;
    int pr = mt ? pr1 : pr0;
    if (gi < n_e) {
      float* orow = out + (size_t)pr * 256;
#pragma unroll
      for (int ct = 0; ct < 16; ++ct) {
        f32x4 bv = *reinterpret_cast<const f32x4*>(b2e + ct * 16 + quad * 4);
        f32x4 o = acc[mt][ct] + bv;
        *reinterpret_cast<f32x4*>(orow + ct * 16 + quad * 4) = o;
      }
    }
  }
}

extern "C" void kernel_launch(void* const* d_in, const int* in_sizes, int n_in,
                              void* d_out, int out_size, void* d_ws, size_t ws_size,
                              hipStream_t stream) {
  const float* x  = (const float*)d_in[0];
  const float* rw = (const float*)d_in[1];
  const float* W1 = (const float*)d_in[2];
  const float* b1 = (const float*)d_in[3];
  const float* W2 = (const float*)d_in[4];
  const float* b2 = (const float*)d_in[5];
  const int* eids = (const int*)d_in[6];
  float* out = (float*)d_out;

  char* ws = (char*)d_ws;
  ushort_t* xn  = (ushort_t*)(ws);              // 16,777,216 B
  ushort_t* w1f = (ushort_t*)(ws + 16777216);   //  4,194,304 B
  ushort_t* w2f = (ushort_t*)(ws + 20971520);   //  4,194,304 B
  int* cnt      = (int*)(ws + 25165824);        //  256 B (8 used)
  int* lists    = (int*)(ws + 25166080);        //  2,097,152 B

  hipMemsetAsync(cnt, 0, 8 * sizeof(int), stream);
  rmsnorm_cast<<<8192, 256, 0, stream>>>(x, rw, xn);
  pack_w<<<512, 256, 0, stream>>>(W1, W2, w1f, w2f);
  route_pairs<<<256, 256, 0, stream>>>(eids, cnt, lists);
  moe_mlp<<<519, 256, 0, stream>>>(xn, w1f, w2f, b1, b2, cnt, lists, out);
}

// Round 3
// 224.633 us; speedup vs baseline: 1.1571x; 1.1571x over previous
//
#include <hip/hip_runtime.h>
#include <cstdint>

typedef unsigned short ushort_t;
typedef __bf16 bf16x8 __attribute__((ext_vector_type(8)));
typedef ushort_t u16x8 __attribute__((ext_vector_type(8)));
typedef float f32x4 __attribute__((ext_vector_type(4)));
typedef uint32_t u32x4 __attribute__((ext_vector_type(4)));

#define RMS_EPS 1.1920928955078125e-07f
// B=8 T=4096 C=256 Wh=1024 E=8 K=2 ; tokens NT=32768, pairs NP=65536

__device__ __forceinline__ ushort_t f2bf(float f) {
  uint32_t u = __builtin_bit_cast(uint32_t, f);
  u += 0x7fffu + ((u >> 16) & 1u);   // RNE
  return (ushort_t)(u >> 16);
}

__device__ __forceinline__ void g2l16(const ushort_t* g, ushort_t* l) {
  __builtin_amdgcn_global_load_lds(
      (const __attribute__((address_space(1))) uint32_t*)g,
      (__attribute__((address_space(3))) uint32_t*)l, 16, 0, 0);
}

__device__ __forceinline__ f32x4 mfma32(bf16x8 a, bf16x8 b, f32x4 c) {
  return __builtin_amdgcn_mfma_f32_16x16x32_bf16(a, b, c, 0, 0, 0);
}

// GELU via odd-poly erf approx: gelu(v) = 0.5*v*(1 + E(clamp(v,±2.9)))
// E = x*(a + b x^2 + c x^4 + d x^6) fit to erf(x/sqrt2); |err| <= ~0.005,
// E(2.9)=1.00001 so v>2.9 -> v (exact), v<-2.9 -> ~0 (exact).
// 8 full-rate VALU ops, no transcendentals (was 2 quarter-rate trans + 9 ops).
__device__ __forceinline__ float gelu1(float v) {
  float vc = fminf(fmaxf(v, -2.9f), 2.9f);   // v_med3
  float x2 = vc * vc;
  float p = fmaf(-0.000414256f, x2, 0.0107517f);
  p = fmaf(p, x2, -0.1136149f);
  p = fmaf(p, x2, 0.786301f);
  float E = vc * p;
  float t = 0.5f * v;
  return fmaf(t, E, t);
}

// ---- RMSNorm + cast to bf16: one wave per token ----
__global__ void rmsnorm_cast(const float* __restrict__ x, const float* __restrict__ w,
                             ushort_t* __restrict__ xn) {
  int token = blockIdx.x * 4 + (threadIdx.x >> 6);
  int lane = threadIdx.x & 63;
  const float4* row = reinterpret_cast<const float4*>(x + (size_t)token * 256);
  float4 v = row[lane];
  float s = v.x * v.x + v.y * v.y + v.z * v.z + v.w * v.w;
#pragma unroll
  for (int off = 1; off < 64; off <<= 1) s += __shfl_xor(s, off);
  float inv = rsqrtf(s * (1.0f / 256.0f) + RMS_EPS);
  const float4* wr = reinterpret_cast<const float4*>(w);
  float4 wv = wr[lane];
  ushort4 o;
  o.x = f2bf(v.x * inv * wv.x);
  o.y = f2bf(v.y * inv * wv.y);
  o.z = f2bf(v.z * inv * wv.z);
  o.w = f2bf(v.w * inv * wv.w);
  *reinterpret_cast<ushort4*>(xn + (size_t)token * 256 + lane * 4) = o;
}

// ---- pack W1/W2 into MFMA fragment order via LDS tile (coalesced) ----
// W1 (K=32 frags): unit = e*32768 + ch*1024 + kk*128 + nt*64 + lane;
//   elem j = W1[e][kk*32+quad*8+j][ch*32+nt*16+l16]
// W2 (half-interleaved per lane; A-operand of concat-K32 GEMM2):
//   unit U = ((e*32+ch)*16+ct)*64 + lane ; 8 ushorts:
//   elem j   = W2[e][ch*32 +  0 + quad*4+j][ct*16+l16]
//   elem 4+j = W2[e][ch*32 + 16 + quad*4+j][ct*16+l16]
__global__ __launch_bounds__(256) void pack_w(const float* __restrict__ W1,
                                              const float* __restrict__ W2,
                                              ushort_t* __restrict__ w1f,
                                              ushort_t* __restrict__ w2f) {
  __shared__ ushort_t tile[64][130];
  int b = blockIdx.x;
  int isW2 = b >= 256;
  const float* src; ushort_t* dst; int e, kt, wt, rs;
  if (!isW2) { e = b >> 5; kt = (b >> 3) & 3; wt = b & 7; src = W1; dst = w1f; rs = 1024; }
  else { b -= 256; e = b >> 5; kt = (b >> 1) & 15; wt = b & 1; src = W2; dst = w2f; rs = 256; }
  int k0 = kt * 64, c0 = wt * 128;
  const float* sb = src + ((size_t)e << 18) + (size_t)k0 * rs + c0;
  int t = threadIdx.x;
#pragma unroll
  for (int i = 0; i < 8; ++i) {
    int f = i * 1024 + t * 4;          // [0,8192)
    int r = f >> 7, c = f & 127;
    float4 v = *reinterpret_cast<const float4*>(sb + (size_t)r * rs + c);
    ushort2 lo, hi;
    lo.x = f2bf(v.x); lo.y = f2bf(v.y); hi.x = f2bf(v.z); hi.y = f2bf(v.w);
    *reinterpret_cast<ushort2*>(&tile[r][c]) = lo;
    *reinterpret_cast<ushort2*>(&tile[r][c + 2]) = hi;
  }
  __syncthreads();
  int lane = t & 63, l16 = lane & 15, quad = lane >> 4;
  int wave = t >> 6;
  if (!isW2) {
#pragma unroll
    for (int p = 0; p < 4; ++p) {
      int u = p * 256 + t;               // [0,1024)
      int kk2 = (u >> 9) & 1;
      int rr = kk2 * 32 + quad * 8;
      int nt = (u >> 6) & 1, chL = (u >> 7) & 3;
      int cc = chL * 32 + nt * 16 + l16;
      u16x8 o;
#pragma unroll
      for (int j = 0; j < 8; ++j) o[j] = tile[rr + j][cc];
      size_t U = ((size_t)e * 32768) + (size_t)(wt * 4 + chL) * 1024 + (kt * 2 + kk2) * 128 + nt * 64 + lane;
      *reinterpret_cast<u16x8*>(dst + U * 8) = o;
    }
  } else {
#pragma unroll
    for (int p = 0; p < 4; ++p) {
      int u = p * 4 + wave;              // [0,16): chL(2) x ctL(8)
      int chL = u >> 3, ctL = u & 7;
      int cc = ctL * 16 + l16;
      u16x8 o;
#pragma unroll
      for (int j = 0; j < 4; ++j) o[j] = tile[chL * 32 + quad * 4 + j][cc];
#pragma unroll
      for (int j = 0; j < 4; ++j) o[4 + j] = tile[chL * 32 + 16 + quad * 4 + j][cc];
      size_t U = (((size_t)(e * 32 + kt * 2 + chL) * 16) + (wt * 8 + ctL)) * 64 + lane;
      *reinterpret_cast<u16x8*>(dst + U * 8) = o;
    }
  }
}

// ---- route (t,k) pairs into per-expert lists ----
__global__ void route_pairs(const int* __restrict__ eids, int* __restrict__ cnt,
                            int* __restrict__ lists) {
  __shared__ int lcnt[8], lbase[8];
  int tid = threadIdx.x;
  if (tid < 8) lcnt[tid] = 0;
  __syncthreads();
  int p = blockIdx.x * 256 + tid;
  int e = eids[p];
  int lpos = atomicAdd(&lcnt[e], 1);
  __syncthreads();
  if (tid < 8) lbase[tid] = atomicAdd(&cnt[tid], lcnt[tid]);
  __syncthreads();
  lists[e * 65536 + lbase[e] + lpos] = p;
}

// ---- fused expert MLP ----
// OCCUPANCY build: 64 pairs/block, 4 waves x 16 rows. acc = 64 AGPR, afr = 32
// VGPR -> total ~160 regs with __launch_bounds__(256,3) => 3 waves/SIMD =
// 3 blocks/CU (LDS 48KB x 3 = 144KB <= 160KB). Cross-block overlap hides the
// barrier drains + MFMA/ds_read latency that dominated at 1 wave/SIMD.
// Bijective XCD swizzle: 1032 = 8*129 tiles, expert-major -> ~1 expert's 1MB
// packed weights per XCD L2.
__global__ __launch_bounds__(256, 3) void moe_mlp(
    const ushort_t* __restrict__ xn,   // [32768][256] bf16
    const ushort_t* __restrict__ w1f,  // [8][32][8][2][64][8]
    const ushort_t* __restrict__ w2f,  // [8][32][16][64][8]
    const float* __restrict__ b1,      // [8][1024]
    const float* __restrict__ b2,      // [8][256]
    const int* __restrict__ cnt,       // [8]
    const int* __restrict__ lists,     // [8][65536]
    float* __restrict__ out)           // [65536][256]
{
  __shared__ __align__(16) ushort_t w1b[2][8192];   // 2 x 16KB
  __shared__ __align__(16) ushort_t w2b[8192];      // 1 x 16KB

  // bijective XCD swizzle (m204 form): physical blockIdx -> contiguous virtual
  int nwg = gridDim.x;
  int q = nwg >> 3, r = nwg & 7;
  int xcd = blockIdx.x & 7, sub = blockIdx.x >> 3;
  int flat = (xcd < r ? xcd * (q + 1) : r * (q + 1) + (xcd - r) * q) + sub;

  int e = -1, tile = 0, accum = 0, n_e = 0;
#pragma unroll
  for (int i = 0; i < 8; ++i) {
    int c = cnt[i];
    int t = (c + 63) >> 6;
    if (e < 0 && flat < accum + t) { e = i; tile = flat - accum; n_e = c; }
    accum += t;
  }
  if (e < 0) return;
  int start = tile * 64;

  int tid = threadIdx.x;
  int wave = tid >> 6, lane = tid & 63, l16 = lane & 15, quad = lane >> 4;

  const ushort_t* w1e = w1f + ((size_t)e << 18);
  const ushort_t* w2e = w2f + ((size_t)e << 18);
  const int* le = lists + e * 65536;

  // this wave's 16 token rows, register-resident
  int gi = start + wave * 16 + l16;
  int pr = le[(gi < n_e) ? gi : 0];

  // stage W1(0) into buffer 0 (16 x 1KB loads across 4 waves)
#pragma unroll
  for (int j = 0; j < 4; ++j) {
    int p = j * 4 + wave;
    g2l16(w1e + p * 512 + lane * 8, &w1b[0][p * 512]);
  }

  // A fragments: 1 m-tile x full K=256, resident (32 VGPR)
  bf16x8 afr[8];
  {
    const u32x4* ar = reinterpret_cast<const u32x4*>(xn + (size_t)(pr >> 1) * 256);
#pragma unroll
    for (int kk = 0; kk < 8; ++kk)
      afr[kk] = __builtin_bit_cast(bf16x8, ar[kk * 4 + quad]);
  }

  f32x4 acc[16];
#pragma unroll
  for (int ct = 0; ct < 16; ++ct) acc[ct] = (f32x4){0.f, 0.f, 0.f, 0.f};

  const float* b1e = b1 + e * 1024;

  for (int ch = 0; ch < 32; ++ch) {
    int cur = ch & 1;
    __syncthreads();   // W1(ch) staged+visible; w2b free (GEMM2(ch-1) done)

    // stage W2(ch) -> single buffer (lands under GEMM1+GELU)
    {
      const ushort_t* n2 = w2e + ch * 8192;
#pragma unroll
      for (int j = 0; j < 4; ++j) {
        int p = j * 4 + wave;
        g2l16(n2 + p * 512 + lane * 8, &w2b[p * 512]);
      }
    }
    // stage W1(ch+1) -> alternate buffer
    if (ch + 1 < 32) {
      const ushort_t* n1 = w1e + (ch + 1) * 8192;
#pragma unroll
      for (int j = 0; j < 4; ++j) {
        int p = j * 4 + wave;
        g2l16(n1 + p * 512 + lane * 8, &w1b[cur ^ 1][p * 512]);
      }
    }

    int w0 = ch * 32;
    f32x4 bia0 = *reinterpret_cast<const f32x4*>(b1e + w0 + quad * 4);
    f32x4 bia1 = *reinterpret_cast<const f32x4*>(b1e + w0 + 16 + quad * 4);

    // GEMM1 (swapped): hT ; 2 independent chains x 8 deep
    const ushort_t* l1 = w1b[cur];
    f32x4 ht0 = (f32x4){0.f, 0.f, 0.f, 0.f};
    f32x4 ht1 = (f32x4){0.f, 0.f, 0.f, 0.f};
#pragma unroll
    for (int kk = 0; kk < 8; ++kk) {
      bf16x8 wA = *reinterpret_cast<const bf16x8*>(l1 + ((kk * 2 + 0) * 64 + lane) * 8);
      bf16x8 wB = *reinterpret_cast<const bf16x8*>(l1 + ((kk * 2 + 1) * 64 + lane) * 8);
      ht0 = mfma32(wA, afr[kk], ht0);
      ht1 = mfma32(wB, afr[kk], ht1);
    }

    // GELU + bf16 pack in registers. elems 0-3 = nt0 half (w=w0+quad*4+r),
    // elems 4-7 = nt1 half (w=w0+16+quad*4+r) — matches W2 frag interleave.
    u16x8 hp;
#pragma unroll
    for (int rr = 0; rr < 4; ++rr) {
      hp[rr]     = f2bf(gelu1(ht0[rr] + bia0[rr]));
      hp[4 + rr] = f2bf(gelu1(ht1[rr] + bia1[rr]));
    }
    bf16x8 hF = __builtin_bit_cast(bf16x8, hp);

    __syncthreads();   // W2(ch) staged+visible (all waves)

    // GEMM2: yT[16 tok x 256] += W2^T . hT via K=32 MFMA; 16 indep accumulators
#pragma unroll
    for (int ct = 0; ct < 16; ++ct) {
      bf16x8 wq = *reinterpret_cast<const bf16x8*>(w2b + (ct * 64 + lane) * 8);
      acc[ct] = mfma32(wq, hF, acc[ct]);
    }
  }

  // epilogue: +b2, masked float4 store (4 consecutive cols per lane)
  const float* b2e = b2 + e * 256;
  if (gi < n_e) {
    float* orow = out + (size_t)pr * 256;
#pragma unroll
    for (int ct = 0; ct < 16; ++ct) {
      f32x4 bv = *reinterpret_cast<const f32x4*>(b2e + ct * 16 + quad * 4);
      f32x4 o = acc[ct] + bv;
      *reinterpret_cast<f32x4*>(orow + ct * 16 + quad * 4) = o;
    }
  }
}

extern "C" void kernel_launch(void* const* d_in, const int* in_sizes, int n_in,
                              void* d_out, int out_size, void* d_ws, size_t ws_size,
                              hipStream_t stream) {
  const float* x  = (const float*)d_in[0];
  const float* rw = (const float*)d_in[1];
  const float* W1 = (const float*)d_in[2];
  const float* b1 = (const float*)d_in[3];
  const float* W2 = (const float*)d_in[4];
  const float* b2 = (const float*)d_in[5];
  const int* eids = (const int*)d_in[6];
  float* out = (float*)d_out;

  char* ws = (char*)d_ws;
  ushort_t* xn  = (ushort_t*)(ws);              // 16,777,216 B
  ushort_t* w1f = (ushort_t*)(ws + 16777216);   //  4,194,304 B
  ushort_t* w2f = (ushort_t*)(ws + 20971520);   //  4,194,304 B
  int* cnt      = (int*)(ws + 25165824);        //  256 B (8 used)
  int* lists    = (int*)(ws + 25166080);        //  2,097,152 B

  hipMemsetAsync(cnt, 0, 8 * sizeof(int), stream);
  rmsnorm_cast<<<8192, 256, 0, stream>>>(x, rw, xn);
  pack_w<<<512, 256, 0, stream>>>(W1, W2, w1f, w2f);
  route_pairs<<<256, 256, 0, stream>>>(eids, cnt, lists);
  // max tiles = sum_e ceil(c_e/64) <= 65536/64 + 8 = 1032 (= 8*129, clean XCD split)
  moe_mlp<<<1032, 256, 0, stream>>>(xn, w1f, w2f, b1, b2, cnt, lists, out);
}